// Round 1
// baseline (705.462 us; speedup 1.0000x reference)
//
#include <hip/hip_runtime.h>
#include <hip/hip_bf16.h>
#include <cstddef>

// ---------------------------------------------------------------------------
// GCN variational encoder: N nodes, E edges, H=128 hidden, C=64 out.
// Pipeline per layer:  hW = act(in) @ W  (scaled by dinv[row]);
//                      out[n] = dinv[n]*(sum_{s in N(n)} hW[s] + hW[n]) + b
// CSR (dst -> src list) built once with int atomics, reused by all 5 layers.
// No float atomics anywhere -> deterministic up to CSR neighbor order (ulp).
// ---------------------------------------------------------------------------

__global__ void k_zero(int* __restrict__ p, int n) {
    int i = blockIdx.x * 256 + threadIdx.x;
    if (i < n) p[i] = 0;
}

__global__ void k_count(const int* __restrict__ dst, int* __restrict__ deg, int e) {
    int i = blockIdx.x * 256 + threadIdx.x;
    if (i < e) atomicAdd(&deg[dst[i]], 1);
}

// single-block exclusive scan of deg -> row_ptr[0..n]
__global__ __launch_bounds__(1024) void k_scan(const int* __restrict__ deg,
                                               int* __restrict__ row_ptr, int n) {
    __shared__ int part[1024];
    const int t = threadIdx.x;
    const int per = (n + 1023) >> 10;
    const int beg = t * per;
    const int end = min(beg + per, n);
    int s = 0;
    for (int i = beg; i < end; ++i) s += deg[i];
    part[t] = s;
    __syncthreads();
    if (t == 0) {
        int r = 0;
        for (int i = 0; i < 1024; ++i) { int v = part[i]; part[i] = r; r += v; }
    }
    __syncthreads();
    int run = part[t];
    for (int i = beg; i < end; ++i) { row_ptr[i] = run; run += deg[i]; }
    if (end == n && beg < n) row_ptr[n] = run;
}

// cursor = row_ptr copy; dinv = 1/sqrt(deg+1); invdeg unused after fold but kept cheap
__global__ void k_prep(const int* __restrict__ deg, const int* __restrict__ row_ptr,
                       int* __restrict__ cursor, float* __restrict__ dinv, int n) {
    int i = blockIdx.x * 256 + threadIdx.x;
    if (i < n) {
        cursor[i] = row_ptr[i];
        float d = (float)(deg[i] + 1);
        dinv[i] = 1.0f / sqrtf(d);
    }
}

__global__ void k_fill(const int* __restrict__ src, const int* __restrict__ dst,
                       int* __restrict__ cursor, int* __restrict__ col, int e) {
    int i = blockIdx.x * 256 + threadIdx.x;
    if (i < e) {
        int d = dst[i];
        int pos = atomicAdd(&cursor[d], 1);
        col[pos] = src[i];
    }
}

// h0[n][0..127] = emb_W[x[n]][0..127]
__global__ void k_embed(const int* __restrict__ x, const float* __restrict__ embW,
                        float* __restrict__ out, int n) {
    int i = blockIdx.x * 256 + threadIdx.x;
    if (i >= n * 32) return;
    int nn = i >> 5, c4 = (i & 31) * 4;
    int xi = x[nn];
    *(float4*)&out[(size_t)nn * 128 + c4] = *(const float4*)&embW[(size_t)xi * 128 + c4];
}

// out[r][c] = dinv[r] * sum_k act(in[r][k]) * W[k][c]
// BM=64 rows/block, K-chunks of 64 staged in LDS along with the W slab.
template <int K, int COUT, bool RELU>
__global__ __launch_bounds__(256) void k_matmul(const float* __restrict__ in,
                                                const float* __restrict__ W,
                                                const float* __restrict__ dinv,
                                                float* __restrict__ out, int n) {
    constexpr int BM = 64, KC = 64;
    constexpr int CT = COUT / 16;      // cols per thread: 8 (COUT=128) or 4 (COUT=64)
    constexpr int LDI = KC + 4;        // pad to break row-stride bank patterns
    __shared__ float sIn[BM * LDI];
    __shared__ float sW[KC * COUT];

    const int tid = threadIdx.x;
    const int row0 = blockIdx.x * BM;
    const int tc = tid & 15;           // 16 col groups
    const int tr = tid >> 4;           // 16 row groups (4 rows each)

    float acc[4][CT];
#pragma unroll
    for (int j = 0; j < 4; ++j)
#pragma unroll
        for (int c = 0; c < CT; ++c) acc[j][c] = 0.f;

    for (int kc = 0; kc < K; kc += KC) {
        // stage input tile (64 rows x 64 k), act applied here
        {
            const int r = tid >> 4;
            const int k4 = (tid & 15) * 4;
#pragma unroll
            for (int p = 0; p < BM / 16; ++p) {
                int rr = p * 16 + r;
                int gr = row0 + rr;
                float4 v = {0.f, 0.f, 0.f, 0.f};
                if (gr < n) v = *(const float4*)&in[(size_t)gr * K + kc + k4];
                if (RELU) {
                    v.x = fmaxf(v.x, 0.f); v.y = fmaxf(v.y, 0.f);
                    v.z = fmaxf(v.z, 0.f); v.w = fmaxf(v.w, 0.f);
                }
                *(float4*)&sIn[rr * LDI + k4] = v;
            }
        }
        // stage W slab (KC x COUT), linear copy
        for (int f4 = tid; f4 < KC * COUT / 4; f4 += 256) {
            *(float4*)&sW[f4 * 4] = *(const float4*)&W[(size_t)kc * COUT + f4 * 4];
        }
        __syncthreads();

#pragma unroll 8
        for (int kk = 0; kk < KC; ++kk) {
            float a[4];
#pragma unroll
            for (int j = 0; j < 4; ++j) a[j] = sIn[(tr * 4 + j) * LDI + kk];
            float4 w0 = *(const float4*)&sW[kk * COUT + tc * 4];
#pragma unroll
            for (int j = 0; j < 4; ++j) {
                acc[j][0] = fmaf(a[j], w0.x, acc[j][0]);
                acc[j][1] = fmaf(a[j], w0.y, acc[j][1]);
                acc[j][2] = fmaf(a[j], w0.z, acc[j][2]);
                acc[j][3] = fmaf(a[j], w0.w, acc[j][3]);
            }
            if constexpr (CT == 8) {
                float4 w1 = *(const float4*)&sW[kk * COUT + COUT / 2 + tc * 4];
#pragma unroll
                for (int j = 0; j < 4; ++j) {
                    acc[j][4] = fmaf(a[j], w1.x, acc[j][4]);
                    acc[j][5] = fmaf(a[j], w1.y, acc[j][5]);
                    acc[j][6] = fmaf(a[j], w1.z, acc[j][6]);
                    acc[j][7] = fmaf(a[j], w1.w, acc[j][7]);
                }
            }
        }
        __syncthreads();
    }

    // write, scaled by dinv[row]  (hW_scaled = hW * dinv)
#pragma unroll
    for (int j = 0; j < 4; ++j) {
        int gr = row0 + tr * 4 + j;
        if (gr < n) {
            float dv = dinv[gr];
            float4 o0 = {acc[j][0] * dv, acc[j][1] * dv, acc[j][2] * dv, acc[j][3] * dv};
            *(float4*)&out[(size_t)gr * COUT + tc * 4] = o0;
            if constexpr (CT == 8) {
                float4 o1 = {acc[j][4] * dv, acc[j][5] * dv, acc[j][6] * dv, acc[j][7] * dv};
                *(float4*)&out[(size_t)gr * COUT + COUT / 2 + tc * 4] = o1;
            }
        }
    }
}

// out[n] = dinv[n] * (sum_{s in N(n)} hWs[s] + hWs[n]) + b     (hWs pre-scaled by dinv)
// one wave per node; VEC = floats per lane (C = VEC*64)
template <int VEC>
__global__ __launch_bounds__(256) void k_gather(const float* __restrict__ hWs,
                                                const int* __restrict__ rptr,
                                                const int* __restrict__ col,
                                                const float* __restrict__ dinv,
                                                const float* __restrict__ b,
                                                float* __restrict__ out, int n) {
    const int wave = threadIdx.x >> 6;
    const int lane = threadIdx.x & 63;
    const int node = blockIdx.x * 4 + wave;
    if (node >= n) return;
    const int beg = rptr[node], end = rptr[node + 1];

    if constexpr (VEC == 2) {
        const float2* h2 = (const float2*)hWs;
        float ax = 0.f, ay = 0.f;
        for (int j = beg; j < end; ++j) {
            int s = col[j];
            float2 v = h2[(size_t)s * 64 + lane];
            ax += v.x; ay += v.y;
        }
        float2 self = h2[(size_t)node * 64 + lane];
        float dn = dinv[node];
        float2 bb = ((const float2*)b)[lane];
        float2 o = {(ax + self.x) * dn + bb.x, (ay + self.y) * dn + bb.y};
        ((float2*)out)[(size_t)node * 64 + lane] = o;
    } else {
        float a = 0.f;
        for (int j = beg; j < end; ++j) {
            int s = col[j];
            a += hWs[(size_t)s * 64 + lane];
        }
        float dn = dinv[node];
        float o = (a + hWs[(size_t)node * 64 + lane]) * dn + b[lane];
        out[(size_t)node * 64 + lane] = o;
    }
}

extern "C" void kernel_launch(void* const* d_in, const int* in_sizes, int n_in,
                              void* d_out, int out_size, void* d_ws, size_t ws_size,
                              hipStream_t stream) {
    const int*   x    = (const int*)d_in[0];
    const int*   ei   = (const int*)d_in[1];
    const float* embW = (const float*)d_in[2];
    const float* W1   = (const float*)d_in[3];
    const float* b1   = (const float*)d_in[4];
    const float* W2   = (const float*)d_in[5];
    const float* b2   = (const float*)d_in[6];
    const float* W3   = (const float*)d_in[7];
    const float* b3   = (const float*)d_in[8];
    const float* Wmu  = (const float*)d_in[9];
    const float* bmu  = (const float*)d_in[10];
    const float* Wls  = (const float*)d_in[11];
    const float* bls  = (const float*)d_in[12];

    const int n = in_sizes[0];        // x is (N,1)
    const int e = in_sizes[1] / 2;
    const int* src = ei;
    const int* dst = ei + e;

    char* w = (char*)d_ws;
    auto alloc = [&](size_t bytes) {
        char* p = w;
        w += (bytes + 255) & ~(size_t)255;
        return p;
    };
    float* bufA = (float*)alloc((size_t)n * 128 * 4);
    float* bufB = (float*)alloc((size_t)n * 128 * 4);
    float* hW   = (float*)alloc((size_t)n * 128 * 4);
    int*   deg  = (int*)alloc((size_t)n * 4);
    int*   rptr = (int*)alloc((size_t)(n + 1) * 4);
    int*   cur  = (int*)alloc((size_t)n * 4);
    int*   col  = (int*)alloc((size_t)e * 4);
    float* dinv = (float*)alloc((size_t)n * 4);

    // ---- graph prep (once per call, reused by all 5 layers) ----
    k_zero <<<(n + 255) / 256, 256, 0, stream>>>(deg, n);
    k_count<<<(e + 255) / 256, 256, 0, stream>>>(dst, deg, e);
    k_scan <<<1, 1024, 0, stream>>>(deg, rptr, n);
    k_prep <<<(n + 255) / 256, 256, 0, stream>>>(deg, rptr, cur, dinv, n);
    k_fill <<<(e + 255) / 256, 256, 0, stream>>>(src, dst, cur, col, e);
    k_embed<<<(n * 32 + 255) / 256, 256, 0, stream>>>(x, embW, bufA, n);

    const int gmm = (n + 63) / 64;
    const int ggt = (n + 3) / 4;
    float* mu = (float*)d_out;
    float* ls = (float*)d_out + (size_t)n * 64;

    // layer 1: H->H, input raw embedding
    k_matmul<128, 128, false><<<gmm, 256, 0, stream>>>(bufA, W1, dinv, hW, n);
    k_gather<2><<<ggt, 256, 0, stream>>>(hW, rptr, col, dinv, b1, bufB, n);
    // layer 2: H->H, relu on input
    k_matmul<128, 128, true><<<gmm, 256, 0, stream>>>(bufB, W2, dinv, hW, n);
    k_gather<2><<<ggt, 256, 0, stream>>>(hW, rptr, col, dinv, b2, bufA, n);
    // layer 3: H->C, relu on input
    k_matmul<128, 64, true><<<gmm, 256, 0, stream>>>(bufA, W3, dinv, hW, n);
    k_gather<1><<<ggt, 256, 0, stream>>>(hW, rptr, col, dinv, b3, bufB, n);
    // mu head: C->C, relu on input
    k_matmul<64, 64, true><<<gmm, 256, 0, stream>>>(bufB, Wmu, dinv, hW, n);
    k_gather<1><<<ggt, 256, 0, stream>>>(hW, rptr, col, dinv, bmu, mu, n);
    // logstd head: C->C, relu on input
    k_matmul<64, 64, true><<<gmm, 256, 0, stream>>>(bufB, Wls, dinv, hW, n);
    k_gather<1><<<ggt, 256, 0, stream>>>(hW, rptr, col, dinv, bls, ls, n);
}

// Round 2
// 505.570 us; speedup vs baseline: 1.3954x; 1.3954x over previous
//
#include <hip/hip_runtime.h>
#include <hip/hip_bf16.h>
#include <cstddef>

// ---------------------------------------------------------------------------
// GCN variational encoder: N nodes, E edges, H=128 hidden, C=64 out.
// hW = act(in) @ W, scaled by dinv[row];
// out[n] = dinv[n]*(sum_{s in N(n)} hW[s] + hW[n]) + b
// CSR built once per call with int atomics; gathers are latency-critical ->
// unroll x8 + index prefetch for deep memory-level parallelism.
// ---------------------------------------------------------------------------

__global__ void k_zero(int* __restrict__ p, int n) {
    int i = blockIdx.x * 256 + threadIdx.x;
    if (i < n) p[i] = 0;
}

__global__ void k_count(const int* __restrict__ dst, int* __restrict__ deg, int e) {
    int i = blockIdx.x * 256 + threadIdx.x;
    if (i < e) atomicAdd(&deg[dst[i]], 1);
}

// single-block exclusive scan of deg -> row_ptr[0..n]
__global__ __launch_bounds__(1024) void k_scan(const int* __restrict__ deg,
                                               int* __restrict__ row_ptr, int n) {
    __shared__ int part[1024];
    const int t = threadIdx.x;
    const int per = (n + 1023) >> 10;
    const int beg = t * per;
    const int end = min(beg + per, n);
    int s = 0;
    for (int i = beg; i < end; ++i) s += deg[i];
    part[t] = s;
    __syncthreads();
    if (t == 0) {
        int r = 0;
        for (int i = 0; i < 1024; ++i) { int v = part[i]; part[i] = r; r += v; }
    }
    __syncthreads();
    int run = part[t];
    for (int i = beg; i < end; ++i) { row_ptr[i] = run; run += deg[i]; }
    if (end == n && beg < n) row_ptr[n] = run;
}

__global__ void k_prep(const int* __restrict__ deg, const int* __restrict__ row_ptr,
                       int* __restrict__ cursor, float* __restrict__ dinv, int n) {
    int i = blockIdx.x * 256 + threadIdx.x;
    if (i < n) {
        cursor[i] = row_ptr[i];
        float d = (float)(deg[i] + 1);
        dinv[i] = 1.0f / sqrtf(d);
    }
}

__global__ void k_fill(const int* __restrict__ src, const int* __restrict__ dst,
                       int* __restrict__ cursor, int* __restrict__ col, int e) {
    int i = blockIdx.x * 256 + threadIdx.x;
    if (i < e) {
        int d = dst[i];
        int pos = atomicAdd(&cursor[d], 1);
        col[pos] = src[i];
    }
}

__global__ void k_embed(const int* __restrict__ x, const float* __restrict__ embW,
                        float* __restrict__ out, int n) {
    int i = blockIdx.x * 256 + threadIdx.x;
    if (i >= n * 32) return;
    int nn = i >> 5, c4 = (i & 31) * 4;
    int xi = x[nn];
    *(float4*)&out[(size_t)nn * 128 + c4] = *(const float4*)&embW[(size_t)xi * 128 + c4];
}

// Wcat[k][0..63] = Wmu[k][*], Wcat[k][64..127] = Wls[k][*]   (64x128)
__global__ void k_catW(const float* __restrict__ Wmu, const float* __restrict__ Wls,
                       float* __restrict__ Wcat) {
    int i = blockIdx.x * 256 + threadIdx.x;
    if (i >= 64 * 128) return;
    int k = i >> 7, c = i & 127;
    Wcat[i] = (c < 64) ? Wmu[k * 64 + c] : Wls[k * 64 + (c - 64)];
}

// out[r][c] = dinv[r] * sum_k act(in[r][k]) * W[k][c]
template <int K, int COUT, bool RELU>
__global__ __launch_bounds__(256) void k_matmul(const float* __restrict__ in,
                                                const float* __restrict__ W,
                                                const float* __restrict__ dinv,
                                                float* __restrict__ out, int n) {
    constexpr int BM = 64, KC = 64;
    constexpr int CT = COUT / 16;
    constexpr int LDI = KC + 4;
    __shared__ float sIn[BM * LDI];
    __shared__ float sW[KC * COUT];

    const int tid = threadIdx.x;
    const int row0 = blockIdx.x * BM;
    const int tc = tid & 15;
    const int tr = tid >> 4;

    float acc[4][CT];
#pragma unroll
    for (int j = 0; j < 4; ++j)
#pragma unroll
        for (int c = 0; c < CT; ++c) acc[j][c] = 0.f;

    for (int kc = 0; kc < K; kc += KC) {
        {
            const int r = tid >> 4;
            const int k4 = (tid & 15) * 4;
#pragma unroll
            for (int p = 0; p < BM / 16; ++p) {
                int rr = p * 16 + r;
                int gr = row0 + rr;
                float4 v = {0.f, 0.f, 0.f, 0.f};
                if (gr < n) v = *(const float4*)&in[(size_t)gr * K + kc + k4];
                if (RELU) {
                    v.x = fmaxf(v.x, 0.f); v.y = fmaxf(v.y, 0.f);
                    v.z = fmaxf(v.z, 0.f); v.w = fmaxf(v.w, 0.f);
                }
                *(float4*)&sIn[rr * LDI + k4] = v;
            }
        }
        for (int f4 = tid; f4 < KC * COUT / 4; f4 += 256) {
            *(float4*)&sW[f4 * 4] = *(const float4*)&W[(size_t)kc * COUT + f4 * 4];
        }
        __syncthreads();

#pragma unroll 8
        for (int kk = 0; kk < KC; ++kk) {
            float a[4];
#pragma unroll
            for (int j = 0; j < 4; ++j) a[j] = sIn[(tr * 4 + j) * LDI + kk];
            float4 w0 = *(const float4*)&sW[kk * COUT + tc * 4];
#pragma unroll
            for (int j = 0; j < 4; ++j) {
                acc[j][0] = fmaf(a[j], w0.x, acc[j][0]);
                acc[j][1] = fmaf(a[j], w0.y, acc[j][1]);
                acc[j][2] = fmaf(a[j], w0.z, acc[j][2]);
                acc[j][3] = fmaf(a[j], w0.w, acc[j][3]);
            }
            if constexpr (CT == 8) {
                float4 w1 = *(const float4*)&sW[kk * COUT + COUT / 2 + tc * 4];
#pragma unroll
                for (int j = 0; j < 4; ++j) {
                    acc[j][4] = fmaf(a[j], w1.x, acc[j][4]);
                    acc[j][5] = fmaf(a[j], w1.y, acc[j][5]);
                    acc[j][6] = fmaf(a[j], w1.z, acc[j][6]);
                    acc[j][7] = fmaf(a[j], w1.w, acc[j][7]);
                }
            }
        }
        __syncthreads();
    }

#pragma unroll
    for (int j = 0; j < 4; ++j) {
        int gr = row0 + tr * 4 + j;
        if (gr < n) {
            float dv = dinv[gr];
            float4 o0 = {acc[j][0] * dv, acc[j][1] * dv, acc[j][2] * dv, acc[j][3] * dv};
            *(float4*)&out[(size_t)gr * COUT + tc * 4] = o0;
            if constexpr (CT == 8) {
                float4 o1 = {acc[j][4] * dv, acc[j][5] * dv, acc[j][6] * dv, acc[j][7] * dv};
                *(float4*)&out[(size_t)gr * COUT + COUT / 2 + tc * 4] = o1;
            }
        }
    }
}

// ---- gathers: one wave per node, unroll x8 + index prefetch for MLP ----

template <int VEC>
__global__ __launch_bounds__(256) void k_gather(const float* __restrict__ hWs,
                                                const int* __restrict__ rptr,
                                                const int* __restrict__ col,
                                                const float* __restrict__ dinv,
                                                const float* __restrict__ b,
                                                float* __restrict__ out, int n) {
    const int wave = threadIdx.x >> 6;
    const int lane = threadIdx.x & 63;
    const int node = blockIdx.x * 4 + wave;
    if (node >= n) return;
    const int beg = rptr[node], end = rptr[node + 1];
    int j = beg;

    if constexpr (VEC == 2) {
        const float2* __restrict__ h2 = (const float2*)hWs;
        float ax0 = 0.f, ay0 = 0.f, ax1 = 0.f, ay1 = 0.f;
        if (end - beg >= 8) {
            int s[8];
#pragma unroll
            for (int u = 0; u < 8; ++u) s[u] = col[j + u];
            j += 8;
            while (true) {
                float2 v[8];
#pragma unroll
                for (int u = 0; u < 8; ++u) v[u] = h2[(size_t)s[u] * 64 + lane];
                const bool more = (j + 8 <= end);
                int sn[8];
                if (more) {
#pragma unroll
                    for (int u = 0; u < 8; ++u) sn[u] = col[j + u];
                }
#pragma unroll
                for (int u = 0; u < 4; ++u) { ax0 += v[u].x; ay0 += v[u].y; }
#pragma unroll
                for (int u = 4; u < 8; ++u) { ax1 += v[u].x; ay1 += v[u].y; }
                if (!more) break;
#pragma unroll
                for (int u = 0; u < 8; ++u) s[u] = sn[u];
                j += 8;
            }
        }
        for (; j < end; ++j) {
            int s0 = col[j];
            float2 v = h2[(size_t)s0 * 64 + lane];
            ax0 += v.x; ay0 += v.y;
        }
        float2 self = h2[(size_t)node * 64 + lane];
        float dn = dinv[node];
        float2 bb = ((const float2*)b)[lane];
        float2 o = {(ax0 + ax1 + self.x) * dn + bb.x, (ay0 + ay1 + self.y) * dn + bb.y};
        ((float2*)out)[(size_t)node * 64 + lane] = o;
    } else {
        float a0 = 0.f, a1 = 0.f;
        if (end - beg >= 8) {
            int s[8];
#pragma unroll
            for (int u = 0; u < 8; ++u) s[u] = col[j + u];
            j += 8;
            while (true) {
                float v[8];
#pragma unroll
                for (int u = 0; u < 8; ++u) v[u] = hWs[(size_t)s[u] * 64 + lane];
                const bool more = (j + 8 <= end);
                int sn[8];
                if (more) {
#pragma unroll
                    for (int u = 0; u < 8; ++u) sn[u] = col[j + u];
                }
#pragma unroll
                for (int u = 0; u < 4; ++u) a0 += v[u];
#pragma unroll
                for (int u = 4; u < 8; ++u) a1 += v[u];
                if (!more) break;
#pragma unroll
                for (int u = 0; u < 8; ++u) s[u] = sn[u];
                j += 8;
            }
        }
        for (; j < end; ++j) a0 += hWs[(size_t)col[j] * 64 + lane];
        float dn = dinv[node];
        float o = (a0 + a1 + hWs[(size_t)node * 64 + lane]) * dn + b[lane];
        out[(size_t)node * 64 + lane] = o;
    }
}

// fused mu/logstd gather: hW2 rows are [mu(64) | ls(64)] interleaved as 128 floats
__global__ __launch_bounds__(256) void k_gather_heads(const float* __restrict__ hW2,
                                                      const int* __restrict__ rptr,
                                                      const int* __restrict__ col,
                                                      const float* __restrict__ dinv,
                                                      const float* __restrict__ bmu,
                                                      const float* __restrict__ bls,
                                                      float* __restrict__ mu,
                                                      float* __restrict__ ls, int n) {
    const int wave = threadIdx.x >> 6;
    const int lane = threadIdx.x & 63;
    const int node = blockIdx.x * 4 + wave;
    if (node >= n) return;
    const int beg = rptr[node], end = rptr[node + 1];
    int j = beg;

    const float2* __restrict__ h2 = (const float2*)hW2;
    float ax0 = 0.f, ay0 = 0.f, ax1 = 0.f, ay1 = 0.f;
    if (end - beg >= 8) {
        int s[8];
#pragma unroll
        for (int u = 0; u < 8; ++u) s[u] = col[j + u];
        j += 8;
        while (true) {
            float2 v[8];
#pragma unroll
            for (int u = 0; u < 8; ++u) v[u] = h2[(size_t)s[u] * 64 + lane];
            const bool more = (j + 8 <= end);
            int sn[8];
            if (more) {
#pragma unroll
                for (int u = 0; u < 8; ++u) sn[u] = col[j + u];
            }
#pragma unroll
            for (int u = 0; u < 4; ++u) { ax0 += v[u].x; ay0 += v[u].y; }
#pragma unroll
            for (int u = 4; u < 8; ++u) { ax1 += v[u].x; ay1 += v[u].y; }
            if (!more) break;
#pragma unroll
            for (int u = 0; u < 8; ++u) s[u] = sn[u];
            j += 8;
        }
    }
    for (; j < end; ++j) {
        int s0 = col[j];
        float2 v = h2[(size_t)s0 * 64 + lane];
        ax0 += v.x; ay0 += v.y;
    }
    float2 self = h2[(size_t)node * 64 + lane];
    float dn = dinv[node];
    float ox = (ax0 + ax1 + self.x) * dn;
    float oy = (ay0 + ay1 + self.y) * dn;
    if (lane < 32) {
        float2 bb = ((const float2*)bmu)[lane];
        ((float2*)mu)[(size_t)node * 32 + lane] = {ox + bb.x, oy + bb.y};
    } else {
        float2 bb = ((const float2*)bls)[lane - 32];
        ((float2*)ls)[(size_t)node * 32 + (lane - 32)] = {ox + bb.x, oy + bb.y};
    }
}

extern "C" void kernel_launch(void* const* d_in, const int* in_sizes, int n_in,
                              void* d_out, int out_size, void* d_ws, size_t ws_size,
                              hipStream_t stream) {
    const int*   x    = (const int*)d_in[0];
    const int*   ei   = (const int*)d_in[1];
    const float* embW = (const float*)d_in[2];
    const float* W1   = (const float*)d_in[3];
    const float* b1   = (const float*)d_in[4];
    const float* W2   = (const float*)d_in[5];
    const float* b2   = (const float*)d_in[6];
    const float* W3   = (const float*)d_in[7];
    const float* b3   = (const float*)d_in[8];
    const float* Wmu  = (const float*)d_in[9];
    const float* bmu  = (const float*)d_in[10];
    const float* Wls  = (const float*)d_in[11];
    const float* bls  = (const float*)d_in[12];

    const int n = in_sizes[0];
    const int e = in_sizes[1] / 2;
    const int* src = ei;
    const int* dst = ei + e;

    char* w = (char*)d_ws;
    auto alloc = [&](size_t bytes) {
        char* p = w;
        w += (bytes + 255) & ~(size_t)255;
        return p;
    };
    float* bufA = (float*)alloc((size_t)n * 128 * 4);
    float* bufB = (float*)alloc((size_t)n * 128 * 4);
    float* hW   = (float*)alloc((size_t)n * 128 * 4);
    int*   deg  = (int*)alloc((size_t)n * 4);
    int*   rptr = (int*)alloc((size_t)(n + 1) * 4);
    int*   cur  = (int*)alloc((size_t)n * 4);
    int*   col  = (int*)alloc((size_t)e * 4);
    float* dinv = (float*)alloc((size_t)n * 4);
    float* Wcat = (float*)alloc((size_t)64 * 128 * 4);

    // ---- graph prep (reused by all layers) ----
    k_zero <<<(n + 255) / 256, 256, 0, stream>>>(deg, n);
    k_count<<<(e + 255) / 256, 256, 0, stream>>>(dst, deg, e);
    k_scan <<<1, 1024, 0, stream>>>(deg, rptr, n);
    k_prep <<<(n + 255) / 256, 256, 0, stream>>>(deg, rptr, cur, dinv, n);
    k_fill <<<(e + 255) / 256, 256, 0, stream>>>(src, dst, cur, col, e);
    k_embed<<<(n * 32 + 255) / 256, 256, 0, stream>>>(x, embW, bufA, n);
    k_catW <<<(64 * 128 + 255) / 256, 256, 0, stream>>>(Wmu, Wls, Wcat);

    const int gmm = (n + 63) / 64;
    const int ggt = (n + 3) / 4;
    float* mu = (float*)d_out;
    float* ls = (float*)d_out + (size_t)n * 64;

    // layer 1
    k_matmul<128, 128, false><<<gmm, 256, 0, stream>>>(bufA, W1, dinv, hW, n);
    k_gather<2><<<ggt, 256, 0, stream>>>(hW, rptr, col, dinv, b1, bufB, n);
    // layer 2
    k_matmul<128, 128, true><<<gmm, 256, 0, stream>>>(bufB, W2, dinv, hW, n);
    k_gather<2><<<ggt, 256, 0, stream>>>(hW, rptr, col, dinv, b2, bufA, n);
    // layer 3 (H->C)
    k_matmul<128, 64, true><<<gmm, 256, 0, stream>>>(bufA, W3, dinv, hW, n);
    k_gather<1><<<ggt, 256, 0, stream>>>(hW, rptr, col, dinv, b3, bufB, n);
    // fused heads: hW2 = relu(bufB) @ [Wmu|Wls], then one gather, split write
    k_matmul<64, 128, true><<<gmm, 256, 0, stream>>>(bufB, Wcat, dinv, hW, n);
    k_gather_heads<<<ggt, 256, 0, stream>>>(hW, rptr, col, dinv, bmu, bls, mu, ls, n);
}

// Round 3
// 432.460 us; speedup vs baseline: 1.6313x; 1.1691x over previous
//
#include <hip/hip_runtime.h>
#include <hip/hip_bf16.h>
#include <cstddef>

// ---------------------------------------------------------------------------
// GCN variational encoder: N nodes, E edges, H=128 hidden, C=64 out.
// hW = act(in) @ W, scaled by dinv[row];
// out[n] = dinv[n]*(sum_{s in N(n)} hW[s] + hW[n]) + b
// CSR built once per call (int atomics + 3-phase hierarchical scan).
// Gathers: one wave/node, unroll x8 + index prefetch for MLP depth.
// ---------------------------------------------------------------------------

__global__ void k_count(const int* __restrict__ dst, int* __restrict__ deg, int e) {
    int i = blockIdx.x * 256 + threadIdx.x;
    if (i < e) atomicAdd(&deg[dst[i]], 1);
}

// ---- 3-phase scan over deg[0..n), 1024 elements per block ----

// phase A: bsum[b] = sum of deg[b*1024 .. b*1024+1023]
__global__ __launch_bounds__(256) void k_bsum(const int* __restrict__ deg,
                                              int* __restrict__ bsum, int n) {
    const int t = threadIdx.x;
    const int lane = t & 63, wv = t >> 6;
    const int i0 = blockIdx.x * 1024 + t * 4;
    int s = 0;
#pragma unroll
    for (int u = 0; u < 4; ++u) {
        int i = i0 + u;
        if (i < n) s += deg[i];
    }
#pragma unroll
    for (int d = 1; d < 64; d <<= 1) s += __shfl_down(s, d, 64);
    __shared__ int ws[4];
    if (lane == 0) ws[wv] = s;
    __syncthreads();
    if (t == 0) bsum[blockIdx.x] = ws[0] + ws[1] + ws[2] + ws[3];
}

// phase B: exclusive scan of bsum[0..g) in-place (single wave)
__global__ void k_scanb(int* __restrict__ bsum, int g) {
    const int lane = threadIdx.x;
    int carry = 0;
    for (int c = 0; c < g; c += 64) {
        int i = c + lane;
        int v = (i < g) ? bsum[i] : 0;
#pragma unroll
        for (int d = 1; d < 64; d <<= 1) {
            int w = __shfl_up(v, d, 64);
            if (lane >= d) v += w;
        }
        int tot = __shfl(v, 63, 64);
        int ex = __shfl_up(v, 1, 64);
        if (lane == 0) ex = 0;
        if (i < g) bsum[i] = ex + carry;
        carry += tot;
    }
}

// phase C: rptr[i] = boff[blk] + exclusive-prefix within block; fused prep:
// cursor[i] = rptr[i]; dinv[i] = rsqrt(deg[i]+1). rptr[n] = e (written by blk 0).
__global__ __launch_bounds__(256) void k_scanfinal(const int* __restrict__ deg,
                                                   const int* __restrict__ boff,
                                                   int* __restrict__ rptr,
                                                   int* __restrict__ cursor,
                                                   float* __restrict__ dinv,
                                                   int n, int e) {
    const int t = threadIdx.x;
    const int lane = t & 63, wv = t >> 6;
    const int i0 = blockIdx.x * 1024 + t * 4;
    int d[4];
#pragma unroll
    for (int u = 0; u < 4; ++u) {
        int i = i0 + u;
        d[u] = (i < n) ? deg[i] : 0;
    }
    int tsum = d[0] + d[1] + d[2] + d[3];
    int v = tsum;
#pragma unroll
    for (int dd = 1; dd < 64; dd <<= 1) {
        int w = __shfl_up(v, dd, 64);
        if (lane >= dd) v += w;
    }
    __shared__ int ws[4];
    if (lane == 63) ws[wv] = v;
    __syncthreads();
    int woff = 0;
    for (int w = 0; w < wv; ++w) woff += ws[w];
    int ex = __shfl_up(v, 1, 64);
    if (lane == 0) ex = 0;
    int r = boff[blockIdx.x] + woff + ex;   // exclusive prefix at element i0

#pragma unroll
    for (int u = 0; u < 4; ++u) {
        int i = i0 + u;
        if (i < n) {
            rptr[i] = r;
            cursor[i] = r;
            dinv[i] = 1.0f / sqrtf((float)(d[u] + 1));
            r += d[u];
        }
    }
    if (blockIdx.x == 0 && t == 0) rptr[n] = e;
}

__global__ void k_fill(const int* __restrict__ src, const int* __restrict__ dst,
                       int* __restrict__ cursor, int* __restrict__ col, int e) {
    int i = blockIdx.x * 256 + threadIdx.x;
    if (i < e) {
        int d = dst[i];
        int pos = atomicAdd(&cursor[d], 1);
        col[pos] = src[i];
    }
}

__global__ void k_embed(const int* __restrict__ x, const float* __restrict__ embW,
                        float* __restrict__ out, int n) {
    int i = blockIdx.x * 256 + threadIdx.x;
    if (i >= n * 32) return;
    int nn = i >> 5, c4 = (i & 31) * 4;
    int xi = x[nn];
    *(float4*)&out[(size_t)nn * 128 + c4] = *(const float4*)&embW[(size_t)xi * 128 + c4];
}

// Wcat[k][0..63] = Wmu[k][*], Wcat[k][64..127] = Wls[k][*]   (64x128)
__global__ void k_catW(const float* __restrict__ Wmu, const float* __restrict__ Wls,
                       float* __restrict__ Wcat) {
    int i = blockIdx.x * 256 + threadIdx.x;
    if (i >= 64 * 128) return;
    int k = i >> 7, c = i & 127;
    Wcat[i] = (c < 64) ? Wmu[k * 64 + c] : Wls[k * 64 + (c - 64)];
}

// out[r][c] = dinv[r] * sum_k act(in[r][k]) * W[k][c]
template <int K, int COUT, bool RELU>
__global__ __launch_bounds__(256) void k_matmul(const float* __restrict__ in,
                                                const float* __restrict__ W,
                                                const float* __restrict__ dinv,
                                                float* __restrict__ out, int n) {
    constexpr int BM = 64, KC = 64;
    constexpr int CT = COUT / 16;
    constexpr int LDI = KC + 4;
    __shared__ float sIn[BM * LDI];
    __shared__ float sW[KC * COUT];

    const int tid = threadIdx.x;
    const int row0 = blockIdx.x * BM;
    const int tc = tid & 15;
    const int tr = tid >> 4;

    float acc[4][CT];
#pragma unroll
    for (int j = 0; j < 4; ++j)
#pragma unroll
        for (int c = 0; c < CT; ++c) acc[j][c] = 0.f;

    for (int kc = 0; kc < K; kc += KC) {
        {
            const int r = tid >> 4;
            const int k4 = (tid & 15) * 4;
#pragma unroll
            for (int p = 0; p < BM / 16; ++p) {
                int rr = p * 16 + r;
                int gr = row0 + rr;
                float4 v = {0.f, 0.f, 0.f, 0.f};
                if (gr < n) v = *(const float4*)&in[(size_t)gr * K + kc + k4];
                if (RELU) {
                    v.x = fmaxf(v.x, 0.f); v.y = fmaxf(v.y, 0.f);
                    v.z = fmaxf(v.z, 0.f); v.w = fmaxf(v.w, 0.f);
                }
                *(float4*)&sIn[rr * LDI + k4] = v;
            }
        }
        for (int f4 = tid; f4 < KC * COUT / 4; f4 += 256) {
            *(float4*)&sW[f4 * 4] = *(const float4*)&W[(size_t)kc * COUT + f4 * 4];
        }
        __syncthreads();

#pragma unroll 8
        for (int kk = 0; kk < KC; ++kk) {
            float a[4];
#pragma unroll
            for (int j = 0; j < 4; ++j) a[j] = sIn[(tr * 4 + j) * LDI + kk];
            float4 w0 = *(const float4*)&sW[kk * COUT + tc * 4];
#pragma unroll
            for (int j = 0; j < 4; ++j) {
                acc[j][0] = fmaf(a[j], w0.x, acc[j][0]);
                acc[j][1] = fmaf(a[j], w0.y, acc[j][1]);
                acc[j][2] = fmaf(a[j], w0.z, acc[j][2]);
                acc[j][3] = fmaf(a[j], w0.w, acc[j][3]);
            }
            if constexpr (CT == 8) {
                float4 w1 = *(const float4*)&sW[kk * COUT + COUT / 2 + tc * 4];
#pragma unroll
                for (int j = 0; j < 4; ++j) {
                    acc[j][4] = fmaf(a[j], w1.x, acc[j][4]);
                    acc[j][5] = fmaf(a[j], w1.y, acc[j][5]);
                    acc[j][6] = fmaf(a[j], w1.z, acc[j][6]);
                    acc[j][7] = fmaf(a[j], w1.w, acc[j][7]);
                }
            }
        }
        __syncthreads();
    }

#pragma unroll
    for (int j = 0; j < 4; ++j) {
        int gr = row0 + tr * 4 + j;
        if (gr < n) {
            float dv = dinv[gr];
            float4 o0 = {acc[j][0] * dv, acc[j][1] * dv, acc[j][2] * dv, acc[j][3] * dv};
            *(float4*)&out[(size_t)gr * COUT + tc * 4] = o0;
            if constexpr (CT == 8) {
                float4 o1 = {acc[j][4] * dv, acc[j][5] * dv, acc[j][6] * dv, acc[j][7] * dv};
                *(float4*)&out[(size_t)gr * COUT + COUT / 2 + tc * 4] = o1;
            }
        }
    }
}

// ---- gathers: one wave per node, unroll x8 + index prefetch ----

template <int VEC>
__global__ __launch_bounds__(256) void k_gather(const float* __restrict__ hWs,
                                                const int* __restrict__ rptr,
                                                const int* __restrict__ col,
                                                const float* __restrict__ dinv,
                                                const float* __restrict__ b,
                                                float* __restrict__ out, int n) {
    const int wave = threadIdx.x >> 6;
    const int lane = threadIdx.x & 63;
    const int node = blockIdx.x * 4 + wave;
    if (node >= n) return;
    const int beg = rptr[node], end = rptr[node + 1];
    int j = beg;

    if constexpr (VEC == 2) {
        const float2* __restrict__ h2 = (const float2*)hWs;
        float ax0 = 0.f, ay0 = 0.f, ax1 = 0.f, ay1 = 0.f;
        if (end - beg >= 8) {
            int s[8];
#pragma unroll
            for (int u = 0; u < 8; ++u) s[u] = col[j + u];
            j += 8;
            while (true) {
                float2 v[8];
#pragma unroll
                for (int u = 0; u < 8; ++u) v[u] = h2[(size_t)s[u] * 64 + lane];
                const bool more = (j + 8 <= end);
                int sn[8];
                if (more) {
#pragma unroll
                    for (int u = 0; u < 8; ++u) sn[u] = col[j + u];
                }
#pragma unroll
                for (int u = 0; u < 4; ++u) { ax0 += v[u].x; ay0 += v[u].y; }
#pragma unroll
                for (int u = 4; u < 8; ++u) { ax1 += v[u].x; ay1 += v[u].y; }
                if (!more) break;
#pragma unroll
                for (int u = 0; u < 8; ++u) s[u] = sn[u];
                j += 8;
            }
        }
        for (; j < end; ++j) {
            int s0 = col[j];
            float2 v = h2[(size_t)s0 * 64 + lane];
            ax0 += v.x; ay0 += v.y;
        }
        float2 self = h2[(size_t)node * 64 + lane];
        float dn = dinv[node];
        float2 bb = ((const float2*)b)[lane];
        float2 o = {(ax0 + ax1 + self.x) * dn + bb.x, (ay0 + ay1 + self.y) * dn + bb.y};
        ((float2*)out)[(size_t)node * 64 + lane] = o;
    } else {
        float a0 = 0.f, a1 = 0.f;
        if (end - beg >= 8) {
            int s[8];
#pragma unroll
            for (int u = 0; u < 8; ++u) s[u] = col[j + u];
            j += 8;
            while (true) {
                float v[8];
#pragma unroll
                for (int u = 0; u < 8; ++u) v[u] = hWs[(size_t)s[u] * 64 + lane];
                const bool more = (j + 8 <= end);
                int sn[8];
                if (more) {
#pragma unroll
                    for (int u = 0; u < 8; ++u) sn[u] = col[j + u];
                }
#pragma unroll
                for (int u = 0; u < 4; ++u) a0 += v[u];
#pragma unroll
                for (int u = 4; u < 8; ++u) a1 += v[u];
                if (!more) break;
#pragma unroll
                for (int u = 0; u < 8; ++u) s[u] = sn[u];
                j += 8;
            }
        }
        for (; j < end; ++j) a0 += hWs[(size_t)col[j] * 64 + lane];
        float dn = dinv[node];
        float o = (a0 + a1 + hWs[(size_t)node * 64 + lane]) * dn + b[lane];
        out[(size_t)node * 64 + lane] = o;
    }
}

// fused mu/logstd gather: hW2 rows are [mu(64) | ls(64)] as 128 floats
__global__ __launch_bounds__(256) void k_gather_heads(const float* __restrict__ hW2,
                                                      const int* __restrict__ rptr,
                                                      const int* __restrict__ col,
                                                      const float* __restrict__ dinv,
                                                      const float* __restrict__ bmu,
                                                      const float* __restrict__ bls,
                                                      float* __restrict__ mu,
                                                      float* __restrict__ ls, int n) {
    const int wave = threadIdx.x >> 6;
    const int lane = threadIdx.x & 63;
    const int node = blockIdx.x * 4 + wave;
    if (node >= n) return;
    const int beg = rptr[node], end = rptr[node + 1];
    int j = beg;

    const float2* __restrict__ h2 = (const float2*)hW2;
    float ax0 = 0.f, ay0 = 0.f, ax1 = 0.f, ay1 = 0.f;
    if (end - beg >= 8) {
        int s[8];
#pragma unroll
        for (int u = 0; u < 8; ++u) s[u] = col[j + u];
        j += 8;
        while (true) {
            float2 v[8];
#pragma unroll
            for (int u = 0; u < 8; ++u) v[u] = h2[(size_t)s[u] * 64 + lane];
            const bool more = (j + 8 <= end);
            int sn[8];
            if (more) {
#pragma unroll
                for (int u = 0; u < 8; ++u) sn[u] = col[j + u];
            }
#pragma unroll
            for (int u = 0; u < 4; ++u) { ax0 += v[u].x; ay0 += v[u].y; }
#pragma unroll
            for (int u = 4; u < 8; ++u) { ax1 += v[u].x; ay1 += v[u].y; }
            if (!more) break;
#pragma unroll
            for (int u = 0; u < 8; ++u) s[u] = sn[u];
            j += 8;
        }
    }
    for (; j < end; ++j) {
        int s0 = col[j];
        float2 v = h2[(size_t)s0 * 64 + lane];
        ax0 += v.x; ay0 += v.y;
    }
    float2 self = h2[(size_t)node * 64 + lane];
    float dn = dinv[node];
    float ox = (ax0 + ax1 + self.x) * dn;
    float oy = (ay0 + ay1 + self.y) * dn;
    if (lane < 32) {
        float2 bb = ((const float2*)bmu)[lane];
        ((float2*)mu)[(size_t)node * 32 + lane] = {ox + bb.x, oy + bb.y};
    } else {
        float2 bb = ((const float2*)bls)[lane - 32];
        ((float2*)ls)[(size_t)node * 32 + (lane - 32)] = {ox + bb.x, oy + bb.y};
    }
}

extern "C" void kernel_launch(void* const* d_in, const int* in_sizes, int n_in,
                              void* d_out, int out_size, void* d_ws, size_t ws_size,
                              hipStream_t stream) {
    const int*   x    = (const int*)d_in[0];
    const int*   ei   = (const int*)d_in[1];
    const float* embW = (const float*)d_in[2];
    const float* W1   = (const float*)d_in[3];
    const float* b1   = (const float*)d_in[4];
    const float* W2   = (const float*)d_in[5];
    const float* b2   = (const float*)d_in[6];
    const float* W3   = (const float*)d_in[7];
    const float* b3   = (const float*)d_in[8];
    const float* Wmu  = (const float*)d_in[9];
    const float* bmu  = (const float*)d_in[10];
    const float* Wls  = (const float*)d_in[11];
    const float* bls  = (const float*)d_in[12];

    const int n = in_sizes[0];
    const int e = in_sizes[1] / 2;
    const int* src = ei;
    const int* dst = ei + e;

    char* w = (char*)d_ws;
    auto alloc = [&](size_t bytes) {
        char* p = w;
        w += (bytes + 255) & ~(size_t)255;
        return p;
    };
    float* bufA = (float*)alloc((size_t)n * 128 * 4);
    float* bufB = (float*)alloc((size_t)n * 128 * 4);
    float* hW   = (float*)alloc((size_t)n * 128 * 4);
    int*   deg  = (int*)alloc((size_t)n * 4);
    int*   rptr = (int*)alloc((size_t)(n + 1) * 4);
    int*   cur  = (int*)alloc((size_t)n * 4);
    int*   col  = (int*)alloc((size_t)e * 4);
    float* dinv = (float*)alloc((size_t)n * 4);
    float* Wcat = (float*)alloc((size_t)64 * 128 * 4);
    int*   bsum = (int*)alloc((size_t)256 * 4);

    const int nscan = (n + 1023) / 1024;   // blocks for scan phases

    // ---- graph prep (reused by all layers) ----
    hipMemsetAsync(deg, 0, (size_t)n * 4, stream);
    k_count<<<(e + 255) / 256, 256, 0, stream>>>(dst, deg, e);
    k_bsum <<<nscan, 256, 0, stream>>>(deg, bsum, n);
    k_scanb<<<1, 64, 0, stream>>>(bsum, nscan);
    k_scanfinal<<<nscan, 256, 0, stream>>>(deg, bsum, rptr, cur, dinv, n, e);
    k_fill <<<(e + 255) / 256, 256, 0, stream>>>(src, dst, cur, col, e);
    k_embed<<<(n * 32 + 255) / 256, 256, 0, stream>>>(x, embW, bufA, n);
    k_catW <<<(64 * 128 + 255) / 256, 256, 0, stream>>>(Wmu, Wls, Wcat);

    const int gmm = (n + 63) / 64;
    const int ggt = (n + 3) / 4;
    float* mu = (float*)d_out;
    float* ls = (float*)d_out + (size_t)n * 64;

    // layer 1
    k_matmul<128, 128, false><<<gmm, 256, 0, stream>>>(bufA, W1, dinv, hW, n);
    k_gather<2><<<ggt, 256, 0, stream>>>(hW, rptr, col, dinv, b1, bufB, n);
    // layer 2
    k_matmul<128, 128, true><<<gmm, 256, 0, stream>>>(bufB, W2, dinv, hW, n);
    k_gather<2><<<ggt, 256, 0, stream>>>(hW, rptr, col, dinv, b2, bufA, n);
    // layer 3 (H->C)
    k_matmul<128, 64, true><<<gmm, 256, 0, stream>>>(bufA, W3, dinv, hW, n);
    k_gather<1><<<ggt, 256, 0, stream>>>(hW, rptr, col, dinv, b3, bufB, n);
    // fused heads: hW2 = relu(bufB) @ [Wmu|Wls], then one gather, split write
    k_matmul<64, 128, true><<<gmm, 256, 0, stream>>>(bufB, Wcat, dinv, hW, n);
    k_gather_heads<<<ggt, 256, 0, stream>>>(hW, rptr, col, dinv, bmu, bls, mu, ls, n);
}

// Round 4
// 364.605 us; speedup vs baseline: 1.9349x; 1.1861x over previous
//
#include <hip/hip_runtime.h>
#include <hip/hip_bf16.h>
#include <cstddef>

// ---------------------------------------------------------------------------
// GCN variational encoder: N nodes, E edges, H=128 hidden, C=64 out.
// Uses A(HW) = (AH)W to gather in the narrow domain:
//  L1: table M = embW@W1 has only 28 distinct rows -> LDS-table gather (8B/edge)
//  L2: matmul then 128-wide gather (compulsory per-XCD table stream)
//  L3: matmul (128->64) then 64-wide gather, writes dinv*relu(.)
//  heads: 64-wide gather of relu(h3), then one 64->128 matmul w/ bias+split
// CSR built once per call (int atomics + 3-phase hierarchical scan).
// ---------------------------------------------------------------------------

__global__ void k_count(const int* __restrict__ dst, int* __restrict__ deg, int e) {
    int i = blockIdx.x * 256 + threadIdx.x;
    if (i < e) atomicAdd(&deg[dst[i]], 1);
}

// phase A: bsum[b] = sum of deg[b*1024 .. b*1024+1023]
__global__ __launch_bounds__(256) void k_bsum(const int* __restrict__ deg,
                                              int* __restrict__ bsum, int n) {
    const int t = threadIdx.x;
    const int lane = t & 63, wv = t >> 6;
    const int i0 = blockIdx.x * 1024 + t * 4;
    int s = 0;
#pragma unroll
    for (int u = 0; u < 4; ++u) {
        int i = i0 + u;
        if (i < n) s += deg[i];
    }
#pragma unroll
    for (int d = 1; d < 64; d <<= 1) s += __shfl_down(s, d, 64);
    __shared__ int ws[4];
    if (lane == 0) ws[wv] = s;
    __syncthreads();
    if (t == 0) bsum[blockIdx.x] = ws[0] + ws[1] + ws[2] + ws[3];
}

// phase B: exclusive scan of bsum[0..g) in-place (single wave)
__global__ void k_scanb(int* __restrict__ bsum, int g) {
    const int lane = threadIdx.x;
    int carry = 0;
    for (int c = 0; c < g; c += 64) {
        int i = c + lane;
        int v = (i < g) ? bsum[i] : 0;
#pragma unroll
        for (int d = 1; d < 64; d <<= 1) {
            int w = __shfl_up(v, d, 64);
            if (lane >= d) v += w;
        }
        int tot = __shfl(v, 63, 64);
        int ex = __shfl_up(v, 1, 64);
        if (lane == 0) ex = 0;
        if (i < g) bsum[i] = ex + carry;
        carry += tot;
    }
}

// phase C: rptr/cursor/dinv + packed xd[i] = {x[i], bits(dinv[i])}
__global__ __launch_bounds__(256) void k_scanfinal(const int* __restrict__ deg,
                                                   const int* __restrict__ boff,
                                                   const int* __restrict__ x,
                                                   int* __restrict__ rptr,
                                                   int* __restrict__ cursor,
                                                   float* __restrict__ dinv,
                                                   int2* __restrict__ xd,
                                                   int n, int e) {
    const int t = threadIdx.x;
    const int lane = t & 63, wv = t >> 6;
    const int i0 = blockIdx.x * 1024 + t * 4;
    int d[4];
#pragma unroll
    for (int u = 0; u < 4; ++u) {
        int i = i0 + u;
        d[u] = (i < n) ? deg[i] : 0;
    }
    int v = d[0] + d[1] + d[2] + d[3];
#pragma unroll
    for (int dd = 1; dd < 64; dd <<= 1) {
        int w = __shfl_up(v, dd, 64);
        if (lane >= dd) v += w;
    }
    __shared__ int ws[4];
    if (lane == 63) ws[wv] = v;
    __syncthreads();
    int woff = 0;
    for (int w = 0; w < wv; ++w) woff += ws[w];
    int ex = __shfl_up(v, 1, 64);
    if (lane == 0) ex = 0;
    int r = boff[blockIdx.x] + woff + ex;

#pragma unroll
    for (int u = 0; u < 4; ++u) {
        int i = i0 + u;
        if (i < n) {
            rptr[i] = r;
            cursor[i] = r;
            float dv = 1.0f / sqrtf((float)(d[u] + 1));
            dinv[i] = dv;
            xd[i] = make_int2(x[i], __float_as_int(dv));
            r += d[u];
        }
    }
    if (blockIdx.x == 0 && t == 0) rptr[n] = e;
}

__global__ void k_fill(const int* __restrict__ src, const int* __restrict__ dst,
                       int* __restrict__ cursor, int* __restrict__ col, int e) {
    int i = blockIdx.x * 256 + threadIdx.x;
    if (i < e) {
        int d = dst[i];
        int pos = atomicAdd(&cursor[d], 1);
        col[pos] = src[i];
    }
}

// M = embW (V x 128) @ W1 (128 x 128); 2 rows per block
__global__ __launch_bounds__(256) void k_smallmm(const float* __restrict__ embW,
                                                 const float* __restrict__ W1,
                                                 float* __restrict__ M, int V) {
    const int r = blockIdx.x * 2 + (threadIdx.x >> 7);
    const int c = threadIdx.x & 127;
    if (r >= V) return;
    float a0 = 0.f, a1 = 0.f;
    const float* er = embW + (size_t)r * 128;
#pragma unroll 4
    for (int k = 0; k < 128; k += 2) {
        a0 = fmaf(er[k], W1[(size_t)k * 128 + c], a0);
        a1 = fmaf(er[k + 1], W1[(size_t)(k + 1) * 128 + c], a1);
    }
    M[(size_t)r * 128 + c] = a0 + a1;
}

// Wcat[k][0..63] = Wmu[k][*], Wcat[k][64..127] = Wls[k][*]   (64x128)
__global__ void k_catW(const float* __restrict__ Wmu, const float* __restrict__ Wls,
                       float* __restrict__ Wcat) {
    int i = blockIdx.x * 256 + threadIdx.x;
    if (i >= 64 * 128) return;
    int k = i >> 7, c = i & 127;
    Wcat[i] = (c < 64) ? Wmu[k * 64 + c] : Wls[k * 64 + (c - 64)];
}

// layer-1 gather: M table (V<=32 rows x 128) in LDS; per edge read packed
// xd[s]={x,dinv} (8B, L2-resident) and accumulate dinv * M[x].
// out[node] = dinv[n]*(sum + dinv[n]*M[x[n]]) + b1
__global__ __launch_bounds__(256) void k_gather_l1(const float* __restrict__ M,
                                                   const int* __restrict__ rptr,
                                                   const int* __restrict__ col,
                                                   const int2* __restrict__ xd,
                                                   const float* __restrict__ b,
                                                   float* __restrict__ out,
                                                   int n, int V) {
    __shared__ float sh[32 * 128];
    for (int f = threadIdx.x; f < V * 32; f += 256)
        ((float4*)sh)[f] = ((const float4*)M)[f];
    __syncthreads();

    const int wave = threadIdx.x >> 6;
    const int lane = threadIdx.x & 63;
    const int node = blockIdx.x * 4 + wave;
    if (node >= n) return;
    const int beg = rptr[node], end = rptr[node + 1];
    int j = beg;

    float ax0 = 0.f, ay0 = 0.f, ax1 = 0.f, ay1 = 0.f;
    const int lo = 2 * lane;
    if (end - beg >= 8) {
        int s[8];
#pragma unroll
        for (int u = 0; u < 8; ++u) s[u] = col[j + u];
        j += 8;
        while (true) {
            int2 p[8];
#pragma unroll
            for (int u = 0; u < 8; ++u) p[u] = xd[s[u]];
            const bool more = (j + 8 <= end);
            int sn[8];
            if (more) {
#pragma unroll
                for (int u = 0; u < 8; ++u) sn[u] = col[j + u];
            }
#pragma unroll
            for (int u = 0; u < 8; ++u) {
                float dv = __int_as_float(p[u].y);
                float2 v = *(const float2*)&sh[p[u].x * 128 + lo];
                if (u & 1) { ax1 = fmaf(dv, v.x, ax1); ay1 = fmaf(dv, v.y, ay1); }
                else       { ax0 = fmaf(dv, v.x, ax0); ay0 = fmaf(dv, v.y, ay0); }
            }
            if (!more) break;
#pragma unroll
            for (int u = 0; u < 8; ++u) s[u] = sn[u];
            j += 8;
        }
    }
    for (; j < end; ++j) {
        int2 p = xd[col[j]];
        float dv = __int_as_float(p.y);
        float2 v = *(const float2*)&sh[p.x * 128 + lo];
        ax0 = fmaf(dv, v.x, ax0); ay0 = fmaf(dv, v.y, ay0);
    }
    int2 pn = xd[node];
    float dn = __int_as_float(pn.y);
    float2 sv = *(const float2*)&sh[pn.x * 128 + lo];
    float2 bb = ((const float2*)b)[lane];
    float ox = (ax0 + ax1 + dn * sv.x) * dn + bb.x;
    float oy = (ay0 + ay1 + dn * sv.y) * dn + bb.y;
    ((float2*)out)[(size_t)node * 64 + lane] = {ox, oy};
}

// out[r][c] = dinv[r] * sum_k act(in[r][k]) * W[k][c]
template <int K, int COUT, bool RELU>
__global__ __launch_bounds__(256) void k_matmul(const float* __restrict__ in,
                                                const float* __restrict__ W,
                                                const float* __restrict__ dinv,
                                                float* __restrict__ out, int n) {
    constexpr int BM = 64, KC = 64;
    constexpr int CT = COUT / 16;
    constexpr int LDI = KC + 4;
    __shared__ float sIn[BM * LDI];
    __shared__ float sW[KC * COUT];

    const int tid = threadIdx.x;
    const int row0 = blockIdx.x * BM;
    const int tc = tid & 15;
    const int tr = tid >> 4;

    float acc[4][CT];
#pragma unroll
    for (int j = 0; j < 4; ++j)
#pragma unroll
        for (int c = 0; c < CT; ++c) acc[j][c] = 0.f;

    for (int kc = 0; kc < K; kc += KC) {
        {
            const int r = tid >> 4;
            const int k4 = (tid & 15) * 4;
#pragma unroll
            for (int p = 0; p < BM / 16; ++p) {
                int rr = p * 16 + r;
                int gr = row0 + rr;
                float4 v = {0.f, 0.f, 0.f, 0.f};
                if (gr < n) v = *(const float4*)&in[(size_t)gr * K + kc + k4];
                if (RELU) {
                    v.x = fmaxf(v.x, 0.f); v.y = fmaxf(v.y, 0.f);
                    v.z = fmaxf(v.z, 0.f); v.w = fmaxf(v.w, 0.f);
                }
                *(float4*)&sIn[rr * LDI + k4] = v;
            }
        }
        for (int f4 = tid; f4 < KC * COUT / 4; f4 += 256) {
            *(float4*)&sW[f4 * 4] = *(const float4*)&W[(size_t)kc * COUT + f4 * 4];
        }
        __syncthreads();

#pragma unroll 8
        for (int kk = 0; kk < KC; ++kk) {
            float a[4];
#pragma unroll
            for (int j = 0; j < 4; ++j) a[j] = sIn[(tr * 4 + j) * LDI + kk];
            float4 w0 = *(const float4*)&sW[kk * COUT + tc * 4];
#pragma unroll
            for (int j = 0; j < 4; ++j) {
                acc[j][0] = fmaf(a[j], w0.x, acc[j][0]);
                acc[j][1] = fmaf(a[j], w0.y, acc[j][1]);
                acc[j][2] = fmaf(a[j], w0.z, acc[j][2]);
                acc[j][3] = fmaf(a[j], w0.w, acc[j][3]);
            }
            if constexpr (CT == 8) {
                float4 w1 = *(const float4*)&sW[kk * COUT + COUT / 2 + tc * 4];
#pragma unroll
                for (int j = 0; j < 4; ++j) {
                    acc[j][4] = fmaf(a[j], w1.x, acc[j][4]);
                    acc[j][5] = fmaf(a[j], w1.y, acc[j][5]);
                    acc[j][6] = fmaf(a[j], w1.z, acc[j][6]);
                    acc[j][7] = fmaf(a[j], w1.w, acc[j][7]);
                }
            }
        }
        __syncthreads();
    }

#pragma unroll
    for (int j = 0; j < 4; ++j) {
        int gr = row0 + tr * 4 + j;
        if (gr < n) {
            float dv = dinv[gr];
            float4 o0 = {acc[j][0] * dv, acc[j][1] * dv, acc[j][2] * dv, acc[j][3] * dv};
            *(float4*)&out[(size_t)gr * COUT + tc * 4] = o0;
            if constexpr (CT == 8) {
                float4 o1 = {acc[j][4] * dv, acc[j][5] * dv, acc[j][6] * dv, acc[j][7] * dv};
                *(float4*)&out[(size_t)gr * COUT + COUT / 2 + tc * 4] = o1;
            }
        }
    }
}

// heads matmul: out = g3 (N x 64) @ Wcat (64 x 128); cols 0-63 +bmu -> mu,
// cols 64-127 +bls -> ls. No relu, no dinv scale.
__global__ __launch_bounds__(256) void k_mm_heads(const float* __restrict__ in,
                                                  const float* __restrict__ W,
                                                  const float* __restrict__ bmu,
                                                  const float* __restrict__ bls,
                                                  float* __restrict__ mu,
                                                  float* __restrict__ ls, int n) {
    constexpr int BM = 64, KC = 64, COUT = 128;
    constexpr int LDI = KC + 4;
    __shared__ float sIn[BM * LDI];
    __shared__ float sW[KC * COUT];

    const int tid = threadIdx.x;
    const int row0 = blockIdx.x * BM;
    const int tc = tid & 15;
    const int tr = tid >> 4;

    float acc[4][8];
#pragma unroll
    for (int j = 0; j < 4; ++j)
#pragma unroll
        for (int c = 0; c < 8; ++c) acc[j][c] = 0.f;

    {
        const int r = tid >> 4;
        const int k4 = (tid & 15) * 4;
#pragma unroll
        for (int p = 0; p < BM / 16; ++p) {
            int rr = p * 16 + r;
            int gr = row0 + rr;
            float4 v = {0.f, 0.f, 0.f, 0.f};
            if (gr < n) v = *(const float4*)&in[(size_t)gr * KC + k4];
            *(float4*)&sIn[rr * LDI + k4] = v;
        }
    }
    for (int f4 = tid; f4 < KC * COUT / 4; f4 += 256) {
        *(float4*)&sW[f4 * 4] = *(const float4*)&W[f4 * 4];
    }
    __syncthreads();

#pragma unroll 8
    for (int kk = 0; kk < KC; ++kk) {
        float a[4];
#pragma unroll
        for (int j = 0; j < 4; ++j) a[j] = sIn[(tr * 4 + j) * LDI + kk];
        float4 w0 = *(const float4*)&sW[kk * COUT + tc * 4];
        float4 w1 = *(const float4*)&sW[kk * COUT + 64 + tc * 4];
#pragma unroll
        for (int j = 0; j < 4; ++j) {
            acc[j][0] = fmaf(a[j], w0.x, acc[j][0]);
            acc[j][1] = fmaf(a[j], w0.y, acc[j][1]);
            acc[j][2] = fmaf(a[j], w0.z, acc[j][2]);
            acc[j][3] = fmaf(a[j], w0.w, acc[j][3]);
            acc[j][4] = fmaf(a[j], w1.x, acc[j][4]);
            acc[j][5] = fmaf(a[j], w1.y, acc[j][5]);
            acc[j][6] = fmaf(a[j], w1.z, acc[j][6]);
            acc[j][7] = fmaf(a[j], w1.w, acc[j][7]);
        }
    }

    float4 bm = ((const float4*)bmu)[tc];
    float4 bl = ((const float4*)bls)[tc];
#pragma unroll
    for (int j = 0; j < 4; ++j) {
        int gr = row0 + tr * 4 + j;
        if (gr < n) {
            float4 o0 = {acc[j][0] + bm.x, acc[j][1] + bm.y, acc[j][2] + bm.z, acc[j][3] + bm.w};
            float4 o1 = {acc[j][4] + bl.x, acc[j][5] + bl.y, acc[j][6] + bl.z, acc[j][7] + bl.w};
            *(float4*)&mu[(size_t)gr * 64 + tc * 4] = o0;
            *(float4*)&ls[(size_t)gr * 64 + tc * 4] = o1;
        }
    }
}

// gathers: one wave per node, unroll x8 + index prefetch.
// MODE 0: out = (a+self)*dn + b           (layer output)
// MODE 1: out = dn * relu((a+self)*dn+b)  (layer-3: pre-scale for next gather)
// MODE 2: out = (a+self)*dn               (head pre-gather, no bias)
template <int VEC, int MODE>
__global__ __launch_bounds__(256) void k_gather(const float* __restrict__ hWs,
                                                const int* __restrict__ rptr,
                                                const int* __restrict__ col,
                                                const float* __restrict__ dinv,
                                                const float* __restrict__ b,
                                                float* __restrict__ out, int n) {
    const int wave = threadIdx.x >> 6;
    const int lane = threadIdx.x & 63;
    const int node = blockIdx.x * 4 + wave;
    if (node >= n) return;
    const int beg = rptr[node], end = rptr[node + 1];
    int j = beg;

    if constexpr (VEC == 2) {
        const float2* __restrict__ h2 = (const float2*)hWs;
        float ax0 = 0.f, ay0 = 0.f, ax1 = 0.f, ay1 = 0.f;
        if (end - beg >= 8) {
            int s[8];
#pragma unroll
            for (int u = 0; u < 8; ++u) s[u] = col[j + u];
            j += 8;
            while (true) {
                float2 v[8];
#pragma unroll
                for (int u = 0; u < 8; ++u) v[u] = h2[(size_t)s[u] * 64 + lane];
                const bool more = (j + 8 <= end);
                int sn[8];
                if (more) {
#pragma unroll
                    for (int u = 0; u < 8; ++u) sn[u] = col[j + u];
                }
#pragma unroll
                for (int u = 0; u < 4; ++u) { ax0 += v[u].x; ay0 += v[u].y; }
#pragma unroll
                for (int u = 4; u < 8; ++u) { ax1 += v[u].x; ay1 += v[u].y; }
                if (!more) break;
#pragma unroll
                for (int u = 0; u < 8; ++u) s[u] = sn[u];
                j += 8;
            }
        }
        for (; j < end; ++j) {
            int s0 = col[j];
            float2 v = h2[(size_t)s0 * 64 + lane];
            ax0 += v.x; ay0 += v.y;
        }
        float2 self = h2[(size_t)node * 64 + lane];
        float dn = dinv[node];
        float2 bb = ((const float2*)b)[lane];
        float2 o = {(ax0 + ax1 + self.x) * dn + bb.x, (ay0 + ay1 + self.y) * dn + bb.y};
        ((float2*)out)[(size_t)node * 64 + lane] = o;
    } else {
        float a0 = 0.f, a1 = 0.f;
        if (end - beg >= 8) {
            int s[8];
#pragma unroll
            for (int u = 0; u < 8; ++u) s[u] = col[j + u];
            j += 8;
            while (true) {
                float v[8];
#pragma unroll
                for (int u = 0; u < 8; ++u) v[u] = hWs[(size_t)s[u] * 64 + lane];
                const bool more = (j + 8 <= end);
                int sn[8];
                if (more) {
#pragma unroll
                    for (int u = 0; u < 8; ++u) sn[u] = col[j + u];
                }
#pragma unroll
                for (int u = 0; u < 4; ++u) a0 += v[u];
#pragma unroll
                for (int u = 4; u < 8; ++u) a1 += v[u];
                if (!more) break;
#pragma unroll
                for (int u = 0; u < 8; ++u) s[u] = sn[u];
                j += 8;
            }
        }
        for (; j < end; ++j) a0 += hWs[(size_t)col[j] * 64 + lane];
        float dn = dinv[node];
        float o = (a0 + a1 + hWs[(size_t)node * 64 + lane]) * dn;
        if constexpr (MODE == 0) {
            o += b[lane];
        } else if constexpr (MODE == 1) {
            o = fmaxf(o + b[lane], 0.f) * dn;
        }
        out[(size_t)node * 64 + lane] = o;
    }
}

extern "C" void kernel_launch(void* const* d_in, const int* in_sizes, int n_in,
                              void* d_out, int out_size, void* d_ws, size_t ws_size,
                              hipStream_t stream) {
    const int*   x    = (const int*)d_in[0];
    const int*   ei   = (const int*)d_in[1];
    const float* embW = (const float*)d_in[2];
    const float* W1   = (const float*)d_in[3];
    const float* b1   = (const float*)d_in[4];
    const float* W2   = (const float*)d_in[5];
    const float* b2   = (const float*)d_in[6];
    const float* W3   = (const float*)d_in[7];
    const float* b3   = (const float*)d_in[8];
    const float* Wmu  = (const float*)d_in[9];
    const float* bmu  = (const float*)d_in[10];
    const float* Wls  = (const float*)d_in[11];
    const float* bls  = (const float*)d_in[12];

    const int n = in_sizes[0];
    const int e = in_sizes[1] / 2;
    const int V = in_sizes[2] / 128;    // embedding vocab (28)
    const int* src = ei;
    const int* dst = ei + e;

    char* w = (char*)d_ws;
    auto alloc = [&](size_t bytes) {
        char* p = w;
        w += (bytes + 255) & ~(size_t)255;
        return p;
    };
    float* bufA = (float*)alloc((size_t)n * 128 * 4);
    float* bufB = (float*)alloc((size_t)n * 128 * 4);
    float* hW   = (float*)alloc((size_t)n * 128 * 4);
    int*   deg  = (int*)alloc((size_t)n * 4);
    int*   rptr = (int*)alloc((size_t)(n + 1) * 4);
    int*   cur  = (int*)alloc((size_t)n * 4);
    int*   col  = (int*)alloc((size_t)e * 4);
    float* dinv = (float*)alloc((size_t)n * 4);
    int2*  xd   = (int2*)alloc((size_t)n * 8);
    float* Wcat = (float*)alloc((size_t)64 * 128 * 4);
    float* Msm  = (float*)alloc((size_t)32 * 128 * 4);
    int*   bsum = (int*)alloc((size_t)256 * 4);

    const int nscan = (n + 1023) / 1024;

    // ---- graph prep (reused by all layers) ----
    hipMemsetAsync(deg, 0, (size_t)n * 4, stream);
    k_count<<<(e + 255) / 256, 256, 0, stream>>>(dst, deg, e);
    k_bsum <<<nscan, 256, 0, stream>>>(deg, bsum, n);
    k_scanb<<<1, 64, 0, stream>>>(bsum, nscan);
    k_scanfinal<<<nscan, 256, 0, stream>>>(deg, bsum, x, rptr, cur, dinv, xd, n, e);
    k_fill <<<(e + 255) / 256, 256, 0, stream>>>(src, dst, cur, col, e);
    k_smallmm<<<(V + 1) / 2, 256, 0, stream>>>(embW, W1, Msm, V);
    k_catW <<<(64 * 128 + 255) / 256, 256, 0, stream>>>(Wmu, Wls, Wcat);

    const int gmm = (n + 63) / 64;
    const int ggt = (n + 3) / 4;
    float* mu = (float*)d_out;
    float* ls = (float*)d_out + (size_t)n * 64;

    // layer 1: 28-row LDS-table gather (h1 = conv1 output, pre-relu)
    k_gather_l1<<<ggt, 256, 0, stream>>>(Msm, rptr, col, xd, b1, bufA, n, V);
    // layer 2: matmul (relu on load) + 128-wide gather
    k_matmul<128, 128, true><<<gmm, 256, 0, stream>>>(bufA, W2, dinv, hW, n);
    k_gather<2, 0><<<ggt, 256, 0, stream>>>(hW, rptr, col, dinv, b2, bufB, n);
    // layer 3: matmul 128->64 (relu on load) + 64-wide gather, out = dinv*relu(conv3)
    k_matmul<128, 64, true><<<gmm, 256, 0, stream>>>(bufB, W3, dinv, hW, n);
    k_gather<1, 1><<<ggt, 256, 0, stream>>>(hW, rptr, col, dinv, b3, bufA, n);
    // heads: g3 = A*relu(h3) (64-wide gather), then g3 @ Wcat + bias, split write
    k_gather<1, 2><<<ggt, 256, 0, stream>>>(bufA, rptr, col, dinv, bmu, bufB, n);
    k_mm_heads<<<gmm, 256, 0, stream>>>(bufB, Wcat, bmu, bls, mu, ls, n);
}